// Round 3
// baseline (86.546 us; speedup 1.0000x reference)
//
#include <hip/hip_runtime.h>

// ReduceBoundingBoxes NMS — 2-launch, all-wide version.
//   flat[i,c] = X[c*n+i], n = 6400
//   valid = f0 > 0.9 ; b5 = (f0, f1, f0+f2, f1+f3, f4)
//   stable sort valid desc by score; greedy NMS on b5[:,1:5]
//
// Identities (exact in fp):
//  1) pos(i) = #{j: sj>si} + #{j<i: sj==si} is a strict total order over ALL
//     candidates. For valid i (si>0.9) every counted j is also valid, so
//     pos(i) == reference rank among valid (argsort(-s) is stable). For
//     invalid i, all V valid j beat it, so pos(i) in [V, n) and unique.
//     => one kernel writes EVERY row exactly once: valid -> b5 at pos,
//        invalid -> zeros at pos. No zero-pass, no atomics, no ws init.
//  2) clamped-area==0 boxes have IoU exactly 0 with everything, so greedy
//     NMS == greedy NMS over the positive-area subset only (M ~ 2).
//
// Perf model (rounds 0-2): dur ~= 40us ws-poison fill (in timed path, fixed)
// + ~4.7us per graph node + device work, where work serialized on one CU is
// the killer. K1 keeps every heavy phase wide (100 blocks; 16 waves sweep
// 400-score chunks; tie fixup is chunk-local <=400 iters via eq-partials).
// K2 is O(M^2), M~2: reads per-block counts+entries only (no 128KB scan).

#define BT    1024   // K1 block threads
#define NCH   16     // chunks (=waves) per K1 block
#define CPB   64     // candidates per K1 block
#define CAPB  64     // pos-area list capacity per block (<= CPB, can't overflow)
#define MAXM  256    // K2 total pos-area capacity (M ~ 2 expected)
#define K2T   256    // K2 block threads

// ---- K1: rank + write all rows + collect pos-area entries per block ----
__global__ __launch_bounds__(BT) void k_main(
    const float* __restrict__ X, float* __restrict__ out,
    float* __restrict__ lists, int* __restrict__ counts, int n) {
  __shared__ unsigned pp[CPB][NCH];   // per-candidate per-chunk: gt | eq<<16
  __shared__ int lcnt;
  const int b = blockIdx.x;
  const int t = threadIdx.x;
  const int w = t >> 6;               // wave id = chunk id
  const int l = t & 63;               // lane = candidate slot in block
  const int c = b * CPB + l;          // global candidate index
  const int n4 = n >> 2;
  const int CQ = (n4 + NCH - 1) / NCH;    // quads per chunk (100 for n=6400)
  if (t == 0) lcnt = 0;

  float si = (c < n) ? X[c] : -1.f;

  // sweep this wave's chunk for all 64 lane-candidates (uniform loads)
  const float4* X4 = (const float4*)X;
  const int q0 = w * CQ, q1 = min(q0 + CQ, n4);
  int gt = 0, eq = 0;
  for (int q = q0; q < q1; ++q) {
    float4 v = X4[q];
    gt += (v.x > si) + (v.y > si) + (v.z > si) + (v.w > si);
    eq += (v.x == si) + (v.y == si) + (v.z == si) + (v.w == si);
  }
  if (w == NCH - 1) {                 // scalar tail (none for n=6400)
    for (int j = n4 << 2; j < n; ++j) {
      float sj = X[j];
      gt += (sj > si); eq += (sj == si);
    }
  }
  pp[l][w] = (unsigned)gt | ((unsigned)eq << 16);
  __syncthreads();

  // wave 0: finalize the block's 64 candidates
  if (w == 0 && c < n) {
    int gts = 0, eqs = 0;
    for (int k = 0; k < NCH; ++k) {
      unsigned p = pp[l][k];
      gts += (int)(p & 0xffffu);
      eqs += (int)(p >> 16);
    }
    eqs -= 1;                         // self (j==c) is always counted equal
    int pos = gts;
    if (eqs > 0) {                    // true fp tie: rare; exact stable fixup
      // + #{j < c: X[j] == si}: full chunks strictly below c via eq-partials,
      // plus a <=4*CQ-element scan of c's own chunk.
      const int kc = min(c / (4 * CQ), NCH - 1);
      int lte = 0;
      for (int k = 0; k < kc; ++k) lte += (int)(pp[l][k] >> 16);
      const int start = 4 * kc * CQ;
      for (int j = start; j < c; ++j) lte += (X[j] == si);
      pos += lte;
    }
    float* row = out + (size_t)pos * 5;
    if (si > 0.9f) {                  // valid: write b5 row, maybe list entry
      float f1 = X[n + c], f2 = X[2 * n + c];
      float f3 = X[3 * n + c], f4v = X[4 * n + c];
      float c2 = si + f2, c3 = f1 + f3;             // reference-exact fp
      row[0] = si; row[1] = f1; row[2] = c2; row[3] = c3; row[4] = f4v;
      float bw = fmaxf(c3 - f1, 0.f);
      float bh = fmaxf(f4v - c2, 0.f);
      float area = bw * bh;
      if (area > 0.f) {
        int p = atomicAdd(&lcnt, 1);  // block-local, <= 64, deterministic-ish
        if (p < CAPB) {
          float4* e = (float4*)(lists + ((size_t)b * CAPB + p) * 8);
          e[0] = make_float4(__int_as_float(pos), f1, c2, c3);
          e[1] = make_float4(f4v, area, 0.f, 0.f);
        }
      }
    } else {                          // invalid: unique slot in [V,n) -> zeros
      row[0] = 0.f; row[1] = 0.f; row[2] = 0.f; row[3] = 0.f; row[4] = 0.f;
    }
    if (l == 0) counts[b] = lcnt;     // after wave-0 atomics (same wave)
  }
}

// ---- K2: gather per-block pos-area entries, sort by rank, greedy NMS ----
__global__ __launch_bounds__(K2T) void k_nms(
    const float* __restrict__ lists, const int* __restrict__ counts,
    float* __restrict__ out, int nb) {
  __shared__ int s_m, sflag;
  __shared__ int   prank[MAXM];
  __shared__ float pbox[MAXM][4];
  __shared__ float parea[MAXM];
  __shared__ int   srnk[MAXM];
  __shared__ float sbox[MAXM][4];
  __shared__ float sarea[MAXM];
  __shared__ int   skeep[MAXM];
  const int t = threadIdx.x;
  if (t == 0) s_m = 0;
  __syncthreads();

  // gather (order nondeterministic; rank-sort below makes it deterministic)
  for (int b = t; b < nb; b += K2T) {
    int cb = counts[b];
    if (cb > CAPB) cb = CAPB;
    for (int e = 0; e < cb; ++e) {
      const float4* src = (const float4*)(lists + ((size_t)b * CAPB + e) * 8);
      float4 r0 = src[0], r1 = src[1];
      int p = atomicAdd(&s_m, 1);
      if (p < MAXM) {
        prank[p] = __float_as_int(r0.x);
        pbox[p][0] = r0.y; pbox[p][1] = r0.z; pbox[p][2] = r0.w;
        pbox[p][3] = r1.x;
        parea[p] = r1.y;
      }
    }
  }
  __syncthreads();
  const int M = min(s_m, MAXM);

  // sort by rank (ranks distinct)
  for (int e = t; e < M; e += K2T) {
    int r = prank[e];
    int pos = 0;
    for (int m = 0; m < M; ++m) pos += (prank[m] < r);
    srnk[pos] = r;
    sbox[pos][0] = pbox[e][0]; sbox[pos][1] = pbox[e][1];
    sbox[pos][2] = pbox[e][2]; sbox[pos][3] = pbox[e][3];
    sarea[pos] = parea[e];
    skeep[pos] = 1;
  }
  __syncthreads();

  // greedy NMS (M ~ 2)
  for (int i = 1; i < M; ++i) {
    if (t == 0) sflag = 0;
    __syncthreads();
    if (t < i && skeep[t]) {
      float ltx = fmaxf(sbox[t][0], sbox[i][0]);
      float lty = fmaxf(sbox[t][1], sbox[i][1]);
      float rbx = fminf(sbox[t][2], sbox[i][2]);
      float rby = fminf(sbox[t][3], sbox[i][3]);
      float w = fmaxf(rbx - ltx, 0.f);
      float h = fmaxf(rby - lty, 0.f);
      float inter = w * h;
      float uni = sarea[t] + sarea[i] - inter;
      if (inter / fmaxf(uni, 1e-9f) > 0.5f) sflag = 1;
    }
    __syncthreads();
    if (t == 0 && sflag) skeep[i] = 0;
    __syncthreads();
  }

  // zero suppressed rows
  for (int e = t; e < M; e += K2T) {
    if (!skeep[e]) {
      float* row = out + (size_t)srnk[e] * 5;
      row[0] = 0.f; row[1] = 0.f; row[2] = 0.f; row[3] = 0.f; row[4] = 0.f;
    }
  }
}

// ---- Fallback: verified round-1 single-block kernel (ws too small) ----
#define FB_NTH 1024
#define MAXV   2048
__global__ __launch_bounds__(FB_NTH, 1) void nms_all(
    const float* __restrict__ X, float* __restrict__ out, int n, int out_n) {
  __shared__ __align__(16) float cscore[MAXV];
  __shared__ unsigned int cidx[MAXV];
  __shared__ int s_vcount, s_mcount, sflag;
  __shared__ int   prank[MAXM];
  __shared__ float pbox[MAXM][4];
  __shared__ float parea[MAXM];
  __shared__ int   srnk[MAXM];
  __shared__ float sbox[MAXM][4];
  __shared__ float sarea[MAXM];
  __shared__ int   skeep[MAXM];
  const int t = threadIdx.x;
  if (t == 0) { s_vcount = 0; s_mcount = 0; }
  const float4* X4 = (const float4*)X;
  const int n4 = n >> 2;
  float4 sc0 = make_float4(-1.f, -1.f, -1.f, -1.f);
  float4 sc1 = sc0;
  if (t < n4)           sc0 = X4[t];
  if (t + FB_NTH < n4)  sc1 = X4[t + FB_NTH];
  float4* out4 = (float4*)out;
  const int o4 = out_n >> 2;
  for (int i = t; i < o4; i += FB_NTH) out4[i] = make_float4(0.f, 0.f, 0.f, 0.f);
  for (int i = (o4 << 2) + t; i < out_n; i += FB_NTH) out[i] = 0.f;
  __syncthreads();
  if (t < n4) {
    float v[4] = {sc0.x, sc0.y, sc0.z, sc0.w};
    #pragma unroll
    for (int k = 0; k < 4; ++k)
      if (v[k] > 0.9f) {
        int p = atomicAdd(&s_vcount, 1);
        if (p < MAXV) { cscore[p] = v[k]; cidx[p] = (unsigned)(4 * t + k); }
      }
  }
  if (t + FB_NTH < n4) {
    float v[4] = {sc1.x, sc1.y, sc1.z, sc1.w};
    #pragma unroll
    for (int k = 0; k < 4; ++k)
      if (v[k] > 0.9f) {
        int p = atomicAdd(&s_vcount, 1);
        if (p < MAXV) { cscore[p] = v[k]; cidx[p] = (unsigned)(4 * (t + FB_NTH) + k); }
      }
  }
  for (int i = (n4 << 2) + t; i < n; i += FB_NTH) {
    float s = X[i];
    if (s > 0.9f) {
      int p = atomicAdd(&s_vcount, 1);
      if (p < MAXV) { cscore[p] = s; cidx[p] = (unsigned)i; }
    }
  }
  __syncthreads();
  const int V = min(s_vcount, MAXV);
  const int V4 = (V + 3) & ~3;
  for (int e = V + t; e < V4; e += FB_NTH) cscore[e] = -1.f;
  __syncthreads();
  const float4* c4 = (const float4*)cscore;
  const int nq = V4 >> 2;
  for (int e = t; e < V; e += FB_NTH) {
    float s = cscore[e];
    unsigned idx = cidx[e];
    int gt = 0, eq = 0;
    for (int q = 0; q < nq; ++q) {
      float4 v = c4[q];
      gt += (v.x > s) + (v.y > s) + (v.z > s) + (v.w > s);
      eq += (v.x == s) + (v.y == s) + (v.z == s) + (v.w == s);
    }
    eq -= 1;
    int rank = gt;
    if (eq > 0) {
      int lt = 0;
      for (int m = 0; m < V; ++m) lt += (cscore[m] == s) && (cidx[m] < idx);
      rank += lt;
    }
    float f1 = X[n + idx], f2 = X[2 * n + idx];
    float f3 = X[3 * n + idx], f4v = X[4 * n + idx];
    float c2 = s + f2, c3 = f1 + f3;
    float* row = out + (size_t)rank * 5;
    row[0] = s; row[1] = f1; row[2] = c2; row[3] = c3; row[4] = f4v;
    float w = fmaxf(c3 - f1, 0.f);
    float h = fmaxf(f4v - c2, 0.f);
    float area = w * h;
    if (area > 0.f) {
      int p = atomicAdd(&s_mcount, 1);
      if (p < MAXM) {
        prank[p] = rank;
        pbox[p][0] = f1; pbox[p][1] = c2; pbox[p][2] = c3; pbox[p][3] = f4v;
        parea[p] = area;
      }
    }
  }
  __syncthreads();
  const int M = min(s_mcount, MAXM);
  for (int e = t; e < M; e += FB_NTH) {
    int r = prank[e];
    int pos = 0;
    for (int m = 0; m < M; ++m) pos += (prank[m] < r);
    srnk[pos] = r;
    sbox[pos][0] = pbox[e][0]; sbox[pos][1] = pbox[e][1];
    sbox[pos][2] = pbox[e][2]; sbox[pos][3] = pbox[e][3];
    sarea[pos] = parea[e];
    skeep[pos] = 1;
  }
  __syncthreads();
  for (int i = 1; i < M; ++i) {
    if (t == 0) sflag = 0;
    __syncthreads();
    if (t < i && skeep[t]) {
      float ltx = fmaxf(sbox[t][0], sbox[i][0]);
      float lty = fmaxf(sbox[t][1], sbox[i][1]);
      float rbx = fminf(sbox[t][2], sbox[i][2]);
      float rby = fminf(sbox[t][3], sbox[i][3]);
      float w = fmaxf(rbx - ltx, 0.f);
      float h = fmaxf(rby - lty, 0.f);
      float inter = w * h;
      float uni = sarea[t] + sarea[i] - inter;
      if (inter / fmaxf(uni, 1e-9f) > 0.5f) sflag = 1;
    }
    __syncthreads();
    if (t == 0 && sflag) skeep[i] = 0;
    __syncthreads();
  }
  for (int e = t; e < M; e += FB_NTH) {
    if (!skeep[e]) {
      float* row = out + (size_t)srnk[e] * 5;
      row[0] = 0.f; row[1] = 0.f; row[2] = 0.f; row[3] = 0.f; row[4] = 0.f;
    }
  }
}

extern "C" void kernel_launch(void* const* d_in, const int* in_sizes, int n_in,
                              void* d_out, int out_size, void* d_ws, size_t ws_size,
                              hipStream_t stream) {
  const float* X = (const float*)d_in[0];
  float* out = (float*)d_out;
  int n = in_sizes[0] / 5;             // 6400
  int nb = (n + CPB - 1) / CPB;        // 100
  size_t need = 1024 + (size_t)nb * CAPB * 8 * sizeof(float);
  if (ws_size >= need) {
    int* counts = (int*)d_ws;                       // nb ints, block-owned
    float* lists = (float*)((char*)d_ws + 1024);    // nb * CAPB * 32B
    hipLaunchKernelGGL(k_main, dim3(nb), dim3(BT), 0, stream,
                       X, out, lists, counts, n);
    hipLaunchKernelGGL(k_nms, dim3(1), dim3(K2T), 0, stream,
                       lists, counts, out, nb);
  } else {
    hipLaunchKernelGGL(nms_all, dim3(1), dim3(FB_NTH), 0, stream,
                       X, out, n, out_size);
  }
}

// Round 4
// 65.429 us; speedup vs baseline: 1.3227x; 1.3227x over previous
//
#include <hip/hip_runtime.h>

// ReduceBoundingBoxes NMS, multi-block version.
//   flat[i,c] = X[c*n+i], n = 6400
//   valid = f0 > 0.9 ; b5 = (f0, f1, f0+f2, f1+f3, f4)
//   stable sort valid desc by score; greedy NMS on b5[:,1:5]
//
// Identities used (both exact in fp):
//  1) rank(i) among valid == #{j in [0,n): sj>si || (sj==si && j<i)} for any
//     valid i, since sj>=si>0.9 implies j valid. -> no compaction/sort needed.
//  2) clamped-area==0 boxes have IoU exactly 0 with everything (monotone fp
//     rounding), so greedy NMS == greedy NMS over positive-area subset only.
//
// Pipeline: K1 zero(out, ws) -> K2 rank partial counts (grid 2D, atomics)
//        -> K3 write rows + collect pos-area list -> K4 single-block NMS fixup.
//
// NOTE (rounds 1-3 post-mortem): this exact 4-kernel version measured 65.4 us
// and 65.9 us in two independent sessions. Three structural redesigns
// (1-launch, 2-launch staged, 2-launch all-wide) all regressed (71/78/87 us)
// while the device-bound poison-fill stayed fixed at ~40 us and session infra
// metrics (acquire_s, push_total_s) degraded monotonically — i.e. dur_us is
// dominated by the mandatory ~40 us workspace-poison fill + host-driven reset
// dispatch gaps, not by our <10 us of device work. Reverting to the
// best-evidenced configuration.

#define MAXM  256   // positive-area list capacity (M ~ 1 expected)
#define CHUNK 200   // score elements per rank-chunk (multiple of 4)

// ---- K1: zero output, rank array, counter (harness poisons with 0xAA) ----
__global__ void k_zero(float* __restrict__ out, int out_n,
                       int* __restrict__ ranks, int n, int* __restrict__ cnt) {
  int tid = blockIdx.x * blockDim.x + threadIdx.x;
  int nt = gridDim.x * blockDim.x;
  float4* o4 = (float4*)out;
  int n4 = out_n >> 2;
  for (int i = tid; i < n4; i += nt) o4[i] = make_float4(0.f, 0.f, 0.f, 0.f);
  for (int i = (n4 << 2) + tid; i < out_n; i += nt) out[i] = 0.f;
  int4* r4 = (int4*)ranks;
  int rn4 = n >> 2;
  for (int i = tid; i < rn4; i += nt) r4[i] = make_int4(0, 0, 0, 0);
  for (int i = (rn4 << 2) + tid; i < n; i += nt) ranks[i] = 0;
  if (tid < 16) cnt[tid] = 0;
}

// ---- K2: partial rank counts. block = 64 candidates, blockIdx.y = chunk ----
__global__ __launch_bounds__(64) void k_rank(const float* __restrict__ X,
                                             int* __restrict__ ranks, int n) {
  int i = blockIdx.x * 64 + threadIdx.x;
  int c0 = blockIdx.y * CHUNK;
  int cend = min(c0 + CHUNK, n);
  float si = (i < n) ? X[i] : -1.f;
  bool valid = (i < n) && (si > 0.9f);
  int gt = 0, eq = 0;
  const float4* X4 = (const float4*)(X + c0);
  int nq = (cend - c0) >> 2;
  for (int q = 0; q < nq; ++q) {
    float4 v = X4[q];
    gt += (v.x > si) + (v.y > si) + (v.z > si) + (v.w > si);
    eq += (v.x == si) + (v.y == si) + (v.z == si) + (v.w == si);
  }
  for (int j = c0 + (nq << 2); j < cend; ++j) {
    float sj = X[j];
    gt += (sj > si); eq += (sj == si);
  }
  if (i >= c0 && i < cend) eq -= 1;   // self is always equal; exclude it
  int partial = gt;
  if (__any(valid && eq > 0)) {       // true fp tie in this chunk: rare
    int eqlt = 0;
    for (int j = c0; j < cend; ++j) {
      float sj = X[j];
      eqlt += (sj == si) && (j < i);
    }
    partial = gt + eqlt;              // exact for every lane (0 if no tie)
  }
  if (valid && partial > 0) atomicAdd(&ranks[i], partial);
}

// ---- K3: write b5 rows at final rank; collect positive-area boxes ----
__global__ void k_rows(const float* __restrict__ X, const int* __restrict__ ranks,
                       float* __restrict__ out, float* __restrict__ list,
                       int* __restrict__ cnt, int n) {
  int i = blockIdx.x * blockDim.x + threadIdx.x;
  if (i >= n) return;
  float s = X[i];
  if (!(s > 0.9f)) return;
  int r = ranks[i];
  float f1 = X[n + i], f2 = X[2 * n + i], f3 = X[3 * n + i], f4 = X[4 * n + i];
  float c2 = s + f2, c3 = f1 + f3;
  float* row = out + (size_t)r * 5;
  row[0] = s; row[1] = f1; row[2] = c2; row[3] = c3; row[4] = f4;
  // box = (f1, c2, c3, f4); reference-exact area arithmetic:
  float w = fmaxf(c3 - f1, 0.f);
  float h = fmaxf(f4 - c2, 0.f);
  float area = w * h;
  if (area > 0.f) {
    int p = atomicAdd(cnt, 1);
    if (p < MAXM) {
      float* e = list + (size_t)p * 6;
      e[0] = __int_as_float(r);
      e[1] = f1; e[2] = c2; e[3] = c3; e[4] = f4; e[5] = area;
    }
  }
}

// ---- K4: greedy NMS over positive-area boxes; zero suppressed rows ----
__global__ __launch_bounds__(256) void k_nms(const float* __restrict__ list,
                                             const int* __restrict__ cnt,
                                             float* __restrict__ out) {
  __shared__ int   srank[MAXM];
  __shared__ float sbox[MAXM][4];
  __shared__ float sarea[MAXM];
  __shared__ int   skeep[MAXM];
  __shared__ int   sflag;
  int t = threadIdx.x;
  int M = *cnt;
  if (M > MAXM) M = MAXM;
  // rank-sort (ranks are distinct): position = #{m: rank_m < rank_e}
  for (int e = t; e < M; e += 256) {
    int r = __float_as_int(list[e * 6 + 0]);
    int pos = 0;
    for (int m = 0; m < M; ++m)
      pos += (__float_as_int(list[m * 6 + 0]) < r);
    srank[pos] = r;
    sbox[pos][0] = list[e * 6 + 1];
    sbox[pos][1] = list[e * 6 + 2];
    sbox[pos][2] = list[e * 6 + 3];
    sbox[pos][3] = list[e * 6 + 4];
    sarea[pos] = list[e * 6 + 5];
    skeep[pos] = 1;
  }
  __syncthreads();
  for (int i = 1; i < M; ++i) {
    if (t == 0) sflag = 0;
    __syncthreads();
    if (t < i && skeep[t]) {
      float ltx = fmaxf(sbox[t][0], sbox[i][0]);
      float lty = fmaxf(sbox[t][1], sbox[i][1]);
      float rbx = fminf(sbox[t][2], sbox[i][2]);
      float rby = fminf(sbox[t][3], sbox[i][3]);
      float w = fmaxf(rbx - ltx, 0.f);
      float h = fmaxf(rby - lty, 0.f);
      float inter = w * h;
      float uni = sarea[t] + sarea[i] - inter;
      if (inter / fmaxf(uni, 1e-9f) > 0.5f) sflag = 1;
    }
    __syncthreads();
    if (t == 0 && sflag) skeep[i] = 0;
    __syncthreads();
  }
  for (int e = t; e < M; e += 256) {
    if (!skeep[e]) {
      float* row = out + (size_t)srank[e] * 5;
      row[0] = 0.f; row[1] = 0.f; row[2] = 0.f; row[3] = 0.f; row[4] = 0.f;
    }
  }
}

// ---- Fallback: round-1 single-block kernel (used only if ws too small) ----
#define FB_NTH  1024
#define FB_MAXV 2048
__global__ __launch_bounds__(FB_NTH, 1) void nms_fallback(
    const float* __restrict__ X, float* __restrict__ out, int n, int out_n) {
  __shared__ float cscore[FB_MAXV];
  __shared__ unsigned int cidx[FB_MAXV];
  __shared__ int s_vcount, s_mcount, sflag;
  __shared__ int srank[MAXM];
  __shared__ float sbox[MAXM][4];
  __shared__ float sarea[MAXM];
  __shared__ int skeep[MAXM];
  __shared__ int prank[MAXM];
  __shared__ float pbox[MAXM][4];
  __shared__ float parea[MAXM];
  const int t = threadIdx.x;
  if (t == 0) { s_vcount = 0; s_mcount = 0; }
  float4* out4 = (float4*)out;
  int n4 = out_n >> 2;
  for (int i = t; i < n4; i += FB_NTH) out4[i] = make_float4(0.f, 0.f, 0.f, 0.f);
  for (int i = (n4 << 2) + t; i < out_n; i += FB_NTH) out[i] = 0.f;
  __syncthreads();
  for (int i = t; i < n; i += FB_NTH) {
    float s = X[i];
    if (s > 0.9f) {
      int p = atomicAdd(&s_vcount, 1);
      if (p < FB_MAXV) { cscore[p] = s; cidx[p] = (unsigned int)i; }
    }
  }
  __syncthreads();
  const int V = min(s_vcount, FB_MAXV);
  for (int e = t; e < V; e += FB_NTH) {
    float s = cscore[e];
    unsigned int idx = cidx[e];
    int rank = 0;
    for (int m = 0; m < V; ++m) {
      float sm = cscore[m];
      rank += (sm > s) || (sm == s && cidx[m] < idx);
    }
    float f1 = X[n + idx], f2 = X[2 * n + idx], f3 = X[3 * n + idx], f4 = X[4 * n + idx];
    float c2 = s + f2, c3 = f1 + f3;
    float* row = out + (size_t)rank * 5;
    row[0] = s; row[1] = f1; row[2] = c2; row[3] = c3; row[4] = f4;
    float w = fmaxf(c3 - f1, 0.f), h = fmaxf(f4 - c2, 0.f);
    float area = w * h;
    if (area > 0.f) {
      int p = atomicAdd(&s_mcount, 1);
      if (p < MAXM) {
        prank[p] = rank;
        pbox[p][0] = f1; pbox[p][1] = c2; pbox[p][2] = c3; pbox[p][3] = f4;
        parea[p] = area;
      }
    }
  }
  __syncthreads();
  const int M = min(s_mcount, MAXM);
  for (int e = t; e < M; e += FB_NTH) {
    int r = prank[e];
    int pos = 0;
    for (int m = 0; m < M; ++m) pos += (prank[m] < r);
    srank[pos] = r;
    sbox[pos][0] = pbox[e][0]; sbox[pos][1] = pbox[e][1];
    sbox[pos][2] = pbox[e][2]; sbox[pos][3] = pbox[e][3];
    sarea[pos] = parea[e];
    skeep[pos] = 1;
  }
  __syncthreads();
  for (int i = 1; i < M; ++i) {
    if (t == 0) sflag = 0;
    __syncthreads();
    if (t < i && skeep[t]) {
      float ltx = fmaxf(sbox[t][0], sbox[i][0]);
      float lty = fmaxf(sbox[t][1], sbox[i][1]);
      float rbx = fminf(sbox[t][2], sbox[i][2]);
      float rby = fminf(sbox[t][3], sbox[i][3]);
      float w = fmaxf(rbx - ltx, 0.f), h = fmaxf(rby - lty, 0.f);
      float inter = w * h;
      float uni = sarea[t] + sarea[i] - inter;
      if (inter / fmaxf(uni, 1e-9f) > 0.5f) sflag = 1;
    }
    __syncthreads();
    if (t == 0 && sflag) skeep[i] = 0;
    __syncthreads();
  }
  for (int e = t; e < M; e += FB_NTH) {
    if (!skeep[e]) {
      float* row = out + (size_t)srank[e] * 5;
      row[0] = 0.f; row[1] = 0.f; row[2] = 0.f; row[3] = 0.f; row[4] = 0.f;
    }
  }
}

extern "C" void kernel_launch(void* const* d_in, const int* in_sizes, int n_in,
                              void* d_out, int out_size, void* d_ws, size_t ws_size,
                              hipStream_t stream) {
  const float* X = (const float*)d_in[0];
  float* out = (float*)d_out;
  int n = in_sizes[0] / 5;   // 6400
  size_t need = 64 + (size_t)n * sizeof(int) + (size_t)MAXM * 6 * sizeof(float);
  if (ws_size >= need) {
    int* cnt = (int*)d_ws;
    int* ranks = (int*)((char*)d_ws + 64);
    float* list = (float*)((char*)d_ws + 64 + (size_t)n * sizeof(int));
    int groups = (n + 63) / 64;
    int chunks = (n + CHUNK - 1) / CHUNK;
    hipLaunchKernelGGL(k_zero, dim3(80), dim3(256), 0, stream, out, out_size, ranks, n, cnt);
    hipLaunchKernelGGL(k_rank, dim3(groups, chunks), dim3(64), 0, stream, X, ranks, n);
    hipLaunchKernelGGL(k_rows, dim3((n + 255) / 256), dim3(256), 0, stream, X, ranks, out, list, cnt, n);
    hipLaunchKernelGGL(k_nms, dim3(1), dim3(256), 0, stream, list, cnt, out);
  } else {
    hipLaunchKernelGGL(nms_fallback, dim3(1), dim3(FB_NTH), 0, stream, X, out, n, out_size);
  }
}